// Round 2
// baseline (203.307 us; speedup 1.0000x reference)
//
#include <hip/hip_runtime.h>
#include <stdint.h>

typedef __bf16 bf16x8 __attribute__((ext_vector_type(8)));
typedef float floatx4 __attribute__((ext_vector_type(4)));
typedef uint32_t uint32x4 __attribute__((ext_vector_type(4)));

#define GRID_W   15
#define PAD_W    17
#define CELLS    221      // 13*17 padded cells
#define HEXDIM   64
#define NHEX     165
#define OUTC     64
#define KDIM     448
#define LSTRIDE  72       // bf16 elements per cell in LDS (64 data + 8 pad)
#define LWORDS   (LSTRIDE/2)   // 36 uint32 words per cell

// round-to-nearest-even fp32 -> bf16, packed pair
__device__ __forceinline__ uint32_t pack2bf(float a, float b) {
    union { float f; uint32_t u; } ua, ub;
    ua.f = a; ub.f = b;
    uint32_t ra = (ua.u + 0x7fffu + ((ua.u >> 16) & 1u)) >> 16;
    uint32_t rb = (ub.u + 0x7fffu + ((ub.u >> 16) & 1u)) >> 16;
    return ra | (rb << 16);
}

__global__ __launch_bounds__(256, 2)
void hexconv_kernel(const float* __restrict__ x,
                    const float* __restrict__ W,
                    const float* __restrict__ bias,
                    float* __restrict__ out)
{
    // padded 13x17 hex grid, bf16, stored as uint32 pairs. 31,824 B.
    __shared__ __align__(16) uint32_t sx[CELLS * LWORDS];

    const int tid  = threadIdx.x;
    const int b    = blockIdx.x;
    const int wave = tid >> 6;
    const int lane = tid & 63;
    const int col  = lane & 15;   // A-row m / B-col n(=o) / C-col
    const int kq   = lane >> 4;   // k-quad: k = kq*8 + j

    // ---- W B-fragments: wave owns output channels [wave*16, wave*16+16) ----
    // Vectorized float4 loads (16B aligned: o*448*4 and ks*128 are 16B multiples).
    const int o = wave * 16 + col;
    uint32x4 bw[14];              // each holds 8 bf16 = one K-step B fragment
    {
        const float* wrow = W + (size_t)o * KDIM + kq * 8;
        #pragma unroll
        for (int ks = 0; ks < 14; ++ks) {
            float4 v0 = *(const float4*)(wrow + ks * 32);
            float4 v1 = *(const float4*)(wrow + ks * 32 + 4);
            uint32x4 t;
            t[0] = pack2bf(v0.x, v0.y);
            t[1] = pack2bf(v0.z, v0.w);
            t[2] = pack2bf(v1.x, v1.y);
            t[3] = pack2bf(v1.z, v1.w);
            bw[ks] = t;
        }
    }
    const float bias_o = bias[o];

    // ---- zero LDS (halo cells must read as 0) ----
    for (int i = tid; i < CELLS * LWORDS; i += 256) sx[i] = 0u;
    __syncthreads();

    // ---- stage sample b: fp32 global -> bf16 padded LDS grid ----
    {
        const float4* xs = (const float4*)(x + (size_t)b * NHEX * HEXDIM);
        for (int i = tid; i < NHEX * HEXDIM / 4; i += 256) {
            int n = i >> 4;            // 16 float4 per hex
            int d = i & 15;            // which float4 within the hex
            float4 v = xs[i];
            int y0 = n / GRID_W, x0 = n - y0 * GRID_W;
            int cell = (y0 + 1) * PAD_W + (x0 + 1);
            uint32_t* dst = sx + cell * LWORDS + d * 2;   // 8B aligned
            uint2 p; p.x = pack2bf(v.x, v.y); p.y = pack2bf(v.z, v.w);
            *(uint2*)dst = p;
        }
    }
    __syncthreads();

    // ---- MFMA GEMM: out[n, o] = sum_k fc_in[n,k] * W[o,k] ----
    float* outb = out + (size_t)b * NHEX * OUTC;

    #pragma unroll 1
    for (int mt = 0; mt < 11; ++mt) {
        int n = mt * 16 + col;           // A row this lane feeds
        bool valid = (n < NHEX);
        int nn = valid ? n : 0;
        int y0 = nn / GRID_W, x0 = nn - y0 * GRID_W;
        int base = (y0 + 1) * PAD_W + (x0 + 1);
        bool use0 = (y0 & 1);            // reference: off0 when (y0+1) even

        const int off0[7] = {-17, -16, -1, 0, 1, 17, 18};
        const int off1[7] = {-18, -17, -1, 0, 1, 16, 17};
        int addr[7];                     // uint32-word addresses
        #pragma unroll
        for (int j = 0; j < 7; ++j) {
            int cell = valid ? (base + (use0 ? off0[j] : off1[j])) : 16; // cell 16 = halo, 0
            addr[j] = cell * LWORDS + kq * 4;
        }

        floatx4 acc = {0.f, 0.f, 0.f, 0.f};
        #pragma unroll
        for (int ks = 0; ks < 14; ++ks) {
            int a_off = addr[ks >> 1] + (ks & 1) * 16;    // neighbor = ks>>1, dim-half = ks&1
            uint32x4 av = *(const uint32x4*)(sx + a_off); // ds_read_b128, 16B aligned
            acc = __builtin_amdgcn_mfma_f32_16x16x32_bf16(
                      __builtin_bit_cast(bf16x8, av),
                      __builtin_bit_cast(bf16x8, bw[ks]),
                      acc, 0, 0, 0);
        }

        // C/D: col = lane&15 (= o-col), row = kq*4 + r
        #pragma unroll
        for (int r = 0; r < 4; ++r) {
            int nr = mt * 16 + kq * 4 + r;
            if (nr < NHEX) outb[(size_t)nr * OUTC + o] = acc[r] + bias_o;
        }
    }
}

extern "C" void kernel_launch(void* const* d_in, const int* in_sizes, int n_in,
                              void* d_out, int out_size, void* d_ws, size_t ws_size,
                              hipStream_t stream) {
    const float* x    = (const float*)d_in[0];
    const float* W    = (const float*)d_in[1];
    const float* bias = (const float*)d_in[2];
    float* out        = (float*)d_out;

    int B = in_sizes[0] / (NHEX * HEXDIM);
    hexconv_kernel<<<B, 256, 0, stream>>>(x, W, bias, out);
}